// Round 8
// baseline (252.074 us; speedup 1.0000x reference)
//
#include <hip/hip_runtime.h>
#include <hip/hip_bf16.h>

#define NROWS 16384   // B*S
#define KD    2048    // D
#define NE    16      // experts
#define ROWS_PER_BLK 64
#define KQ    512     // K-range per K-group
#define TKG   64      // K-floats staged per group per step
#define NSTEP (KQ / TKG)   // 8

// v8: R=4 rows/lane + 4-way in-block K-split.
//  - block = 512 thr / 8 waves; wave w -> (K-group g=w>>1, row-half h=w&1)
//  - lane = (rgrp=lane>>3 -> 4 rows, seg=lane&7 -> 8-float K-slice per step)
//  - per group: private W-stack tile [32 rows][64 K] double-buffered in LDS,
//    staged via async global_load_lds (uniform base + lane*16 dest)
//  - FMA:ds_read ratio 16:1 (vs 4:1 in v7) -> LDS traffic /4
//  - epilogue: shfl butterfly over segs -> slab[4][64][32] -> combine -> row epilogue
// Output FLOAT32: [262144 probs][32768 ids-as-floats].

__device__ __forceinline__ void gload_lds16(const float* g, float* l) {
    __builtin_amdgcn_global_load_lds(
        (const __attribute__((address_space(1))) void*)g,
        (__attribute__((address_space(3))) void*)l,
        16, 0, 0);
}

__global__ __launch_bounds__(512, 2)
void noisy_router_kernel(const float* __restrict__ x,
                         const float* __restrict__ noise,
                         const float* __restrict__ Wfc,
                         const float* __restrict__ bfc,
                         const float* __restrict__ Wns,
                         const float* __restrict__ bns,
                         float* __restrict__ out)
{
    __shared__ float lds[16384];   // 64 KB: wt[4 groups][2 bufs][32*64]; reused by epilogue

    const int tid  = threadIdx.x;
    const int lane = tid & 63;
    const int w    = tid >> 6;     // 0..7
    const int g    = w >> 1;       // K-group 0..3
    const int h    = w & 1;        // row-half 0..1
    const int seg  = lane & 7;
    const int rgrp = lane >> 3;

    const int rowbase = blockIdx.x * ROWS_PER_BLK + h * 32 + rgrp * 4;  // 4 rows
    const int kbase   = g * KQ;

    float* const wt0 = lds + (g * 2 + 0) * 2048;
    float* const wt1 = lds + (g * 2 + 1) * 2048;

    // staging map: wave stages W-stack rows h*16..h*16+15 (4 instrs x 4 rows);
    // instr i: wrow = h*16 + i*4 + (lane>>4), col = (lane&15)*4
    // -> LDS dest = uniform base + lane*16 bytes (required form)
    const int srow = h * 16 + (lane >> 4);
    const int scol = (lane & 15) * 4;

    float accA[4][16], accB[4][16];
    #pragma unroll
    for (int j = 0; j < 4; ++j)
        #pragma unroll
        for (int e = 0; e < NE; ++e) { accA[j][e] = 0.f; accB[j][e] = 0.f; }

    const float* xb[4];
    #pragma unroll
    for (int j = 0; j < 4; ++j)
        xb[j] = x + (size_t)(rowbase + j) * KD + kbase + seg * 8;

    float4 xc[2][4][2];   // [buf][row][half] -- indices static under unroll 2

    // ---- prologue: stage tile 0 + x step 0 ----
    #pragma unroll
    for (int i = 0; i < 4; ++i) {
        const int wrow = srow + i * 4;
        const float* gsrc = (wrow < 16 ? Wfc + (size_t)wrow * KD
                                       : Wns + (size_t)(wrow - 16) * KD) + kbase + scol;
        gload_lds16(gsrc, wt0 + wrow * 64 + scol);
    }
    #pragma unroll
    for (int j = 0; j < 4; ++j) {
        xc[0][j][0] = *(const float4*)(xb[j]);
        xc[0][j][1] = *(const float4*)(xb[j] + 4);
    }

    #pragma unroll 2
    for (int s = 0; s < NSTEP; ++s) {
        __syncthreads();               // drains vmcnt: tile s + x step s ready
        const int cb = s & 1, nb = cb ^ 1;
        float* const wtc = (cb == 0) ? wt0 : wt1;
        float* const wtn = (cb == 0) ? wt1 : wt0;

        if (s + 1 < NSTEP) {           // async-stage tile s+1, prefetch x s+1
            const int k0 = kbase + (s + 1) * TKG;
            #pragma unroll
            for (int i = 0; i < 4; ++i) {
                const int wrow = srow + i * 4;
                const float* gsrc = (wrow < 16 ? Wfc + (size_t)wrow * KD
                                               : Wns + (size_t)(wrow - 16) * KD) + k0 + scol;
                gload_lds16(gsrc, wtn + wrow * 64 + scol);
            }
            #pragma unroll
            for (int j = 0; j < 4; ++j) {
                xc[nb][j][0] = *(const float4*)(xb[j] + (s + 1) * TKG);
                xc[nb][j][1] = *(const float4*)(xb[j] + (s + 1) * TKG + 4);
            }
        }

        const float* wp = wtc + seg * 8;
        #pragma unroll
        for (int e = 0; e < NE; ++e) {
            const float4 a0 = *(const float4*)(wp + e * 64);
            const float4 a1 = *(const float4*)(wp + e * 64 + 4);
            const float4 b0 = *(const float4*)(wp + (16 + e) * 64);
            const float4 b1 = *(const float4*)(wp + (16 + e) * 64 + 4);
            #pragma unroll
            for (int j = 0; j < 4; ++j) {
                const float4 x0 = xc[cb][j][0], x1 = xc[cb][j][1];
                float sA = accA[j][e], sB = accB[j][e];
                sA = fmaf(x0.x, a0.x, sA); sA = fmaf(x0.y, a0.y, sA);
                sA = fmaf(x0.z, a0.z, sA); sA = fmaf(x0.w, a0.w, sA);
                sA = fmaf(x1.x, a1.x, sA); sA = fmaf(x1.y, a1.y, sA);
                sA = fmaf(x1.z, a1.z, sA); sA = fmaf(x1.w, a1.w, sA);
                sB = fmaf(x0.x, b0.x, sB); sB = fmaf(x0.y, b0.y, sB);
                sB = fmaf(x0.z, b0.z, sB); sB = fmaf(x0.w, b0.w, sB);
                sB = fmaf(x1.x, b1.x, sB); sB = fmaf(x1.y, b1.y, sB);
                sB = fmaf(x1.z, b1.z, sB); sB = fmaf(x1.w, b1.w, sB);
                accA[j][e] = sA; accB[j][e] = sB;
            }
        }
    }

    // ---- butterfly over the 8 k-segs (masks 1,2,4 stay within seg-group) ----
    #pragma unroll
    for (int j = 0; j < 4; ++j)
        #pragma unroll
        for (int e = 0; e < NE; ++e) {
            float a = accA[j][e], b = accB[j][e];
            a += __shfl_xor(a, 1); a += __shfl_xor(a, 2); a += __shfl_xor(a, 4);
            b += __shfl_xor(b, 1); b += __shfl_xor(b, 2); b += __shfl_xor(b, 4);
            accA[j][e] = a; accB[j][e] = b;
        }

    __syncthreads();                  // all tile reads done; lds reusable
    float* const slab = lds;          // [4 groups][64 rows][32 outs] = 8192 floats
    float* const red  = lds + 8192;   // [64 rows][stride 36]

    if (seg == 0) {                   // one writer per 4-row group
        const int rl = h * 32 + rgrp * 4;
        #pragma unroll
        for (int j = 0; j < 4; ++j) {
            float* dst = slab + g * 2048 + (rl + j) * 32;
            #pragma unroll
            for (int q = 0; q < 4; ++q) {
                *(float4*)(dst + q * 4)      = *(float4*)&accA[j][q * 4];
                *(float4*)(dst + 16 + q * 4) = *(float4*)&accB[j][q * 4];
            }
        }
    }
    __syncthreads();

    {   // combine 4 group-partials: 512 threads x one float4 (64 rows x 8 quads)
        const int row = tid >> 3, q = tid & 7;
        float4 sum = make_float4(0.f, 0.f, 0.f, 0.f);
        #pragma unroll
        for (int gg = 0; gg < 4; ++gg) {
            const float4 v = *(const float4*)(slab + gg * 2048 + row * 32 + q * 4);
            sum.x += v.x; sum.y += v.y; sum.z += v.z; sum.w += v.w;
        }
        *(float4*)(red + row * 36 + q * 4) = sum;
    }
    __syncthreads();

    // ---- per-row epilogue: softplus noise, top-2, sparse softmax ----
    if (tid < ROWS_PER_BLK) {
        const int r = tid;
        float rv[32];
        #pragma unroll
        for (int q = 0; q < 8; ++q)
            *(float4*)&rv[q * 4] = *(const float4*)(red + r * 36 + q * 4);

        const size_t grow = (size_t)blockIdx.x * ROWS_PER_BLK + r;
        const float* nzp = noise + grow * NE;

        float m1 = -1e30f, m2 = -1e30f;
        int i1 = 0, i2 = 0;
        #pragma unroll
        for (int j = 0; j < NE; ++j) {
            const float z  = rv[16 + j] + bns[j];
            const float sp = fmaxf(z, 0.f) + log1pf(expf(-fabsf(z)));  // jax softplus
            const float v  = fmaf(nzp[j], sp, rv[j] + bfc[j]);
            if (v > m1)      { m2 = m1; i2 = i1; m1 = v; i1 = j; }     // ties -> lower idx
            else if (v > m2) { m2 = v;  i2 = j; }
        }
        const float e2  = expf(m2 - m1);
        const float inv = 1.f / (1.f + e2);

        float* po = out + grow * NE;
        #pragma unroll
        for (int j = 0; j < NE; ++j) {
            po[j] = (j == i1) ? inv : ((j == i2) ? e2 * inv : 0.f);
        }
        float* pi = out + (size_t)NROWS * NE + grow * 2;
        pi[0] = (float)i1;
        pi[1] = (float)i2;
    }
}

extern "C" void kernel_launch(void* const* d_in, const int* in_sizes, int n_in,
                              void* d_out, int out_size, void* d_ws, size_t ws_size,
                              hipStream_t stream)
{
    const float* x     = (const float*)d_in[0];
    const float* noise = (const float*)d_in[1];
    const float* Wfc   = (const float*)d_in[2];
    const float* bfc   = (const float*)d_in[3];
    const float* Wns   = (const float*)d_in[4];
    const float* bns   = (const float*)d_in[5];
    float* out = (float*)d_out;

    noisy_router_kernel<<<NROWS / ROWS_PER_BLK, 512, 0, stream>>>(
        x, noise, Wfc, bfc, Wns, bns, out);
}

// Round 9
// 244.291 us; speedup vs baseline: 1.0319x; 1.0319x over previous
//
#include <hip/hip_runtime.h>
#include <hip/hip_bf16.h>

#define NROWS 16384   // B*S
#define KD    2048    // D
#define NE    16      // experts
#define ROWS_PER_BLK 64
#define KQ    512     // K-range per K-group
#define TKG   64      // K-floats staged per group per step
#define NSTEP (KQ / TKG)   // 8

// v9 = v8 geometry with the spill fixed (explicit 2-phase loop, all static regs).
//  - block = 512 thr / 8 waves; wave w -> (K-group g=w>>1, row-half h=w&1)
//  - lane = (rgrp=lane>>3 -> 4 rows, seg=lane&7 -> 8-float K-slice)
//  - per group: W-stack tile [32][64] double-buffered in LDS via global_load_lds
//  - FMA:ds_read = 16:1; ds_read instrs/CU ~4k (~20us LDS floor)
// Output FLOAT32: [262144 probs][32768 ids-as-floats].

__device__ __forceinline__ void gload_lds16(const float* g, float* l) {
    __builtin_amdgcn_global_load_lds(
        (const __attribute__((address_space(1))) void*)g,
        (__attribute__((address_space(3))) void*)l,
        16, 0, 0);
}

__global__ __launch_bounds__(512, 2)
void noisy_router_kernel(const float* __restrict__ x,
                         const float* __restrict__ noise,
                         const float* __restrict__ Wfc,
                         const float* __restrict__ bfc,
                         const float* __restrict__ Wns,
                         const float* __restrict__ bns,
                         float* __restrict__ out)
{
    __shared__ float lds[16384];   // 64 KB: wt[4 groups][2 bufs][32*64]; epilogue reuse

    const int tid  = threadIdx.x;
    const int lane = tid & 63;
    const int w    = tid >> 6;     // 0..7
    const int g    = w >> 1;       // K-group 0..3
    const int h    = w & 1;        // row-half 0..1
    const int seg  = lane & 7;
    const int rgrp = lane >> 3;

    const int rowbase = blockIdx.x * ROWS_PER_BLK + h * 32 + rgrp * 4;
    const int kbase   = g * KQ;

    float* const wt0 = lds + (g * 2 + 0) * 2048;
    float* const wt1 = lds + (g * 2 + 1) * 2048;

    // staging map: wave stages W-stack rows h*16..h*16+15; instr i covers rows
    // srow+i*4 with col (lane&15)*4 -> LDS dest = uniform base + lane*16 bytes.
    const int srow = h * 16 + (lane >> 4);
    const int scol = (lane & 15) * 4;
    const float* wsrc[4];
    #pragma unroll
    for (int i = 0; i < 4; ++i) {
        const int wrow = srow + i * 4;
        wsrc[i] = (wrow < 16 ? Wfc + (size_t)wrow * KD
                             : Wns + (size_t)(wrow - 16) * KD) + kbase + scol;
    }
    const int sdst = srow * 64 + scol;   // +i*256 per instr

    const float* xptr[4];
    #pragma unroll
    for (int j = 0; j < 4; ++j)
        xptr[j] = x + (size_t)(rowbase + j) * KD + kbase + seg * 8;

    float accA[4][16], accB[4][16];
    #pragma unroll
    for (int j = 0; j < 4; ++j)
        #pragma unroll
        for (int e = 0; e < NE; ++e) { accA[j][e] = 0.f; accB[j][e] = 0.f; }

    float4 xA[4][2], xB[4][2];   // two named x buffers; all indices static

#define STAGE(DST, S)                                                   \
    { _Pragma("unroll")                                                 \
      for (int i = 0; i < 4; ++i)                                       \
          gload_lds16(wsrc[i] + (S) * TKG, (DST) + sdst + i * 256); }

#define XLOAD(XV, S)                                                    \
    { _Pragma("unroll")                                                 \
      for (int j = 0; j < 4; ++j) {                                     \
          XV[j][0] = *(const float4*)(xptr[j] + (S) * TKG);             \
          XV[j][1] = *(const float4*)(xptr[j] + (S) * TKG + 4);         \
      } }

#define COMPUTE(WT, XV)                                                 \
    { const float* wp = (WT) + seg * 8;                                 \
      _Pragma("unroll")                                                 \
      for (int e = 0; e < NE; ++e) {                                    \
          const float4 a0 = *(const float4*)(wp + e * 64);              \
          const float4 a1 = *(const float4*)(wp + e * 64 + 4);          \
          const float4 b0 = *(const float4*)(wp + (16 + e) * 64);       \
          const float4 b1 = *(const float4*)(wp + (16 + e) * 64 + 4);   \
          _Pragma("unroll")                                             \
          for (int j = 0; j < 4; ++j) {                                 \
              const float4 x0 = XV[j][0], x1 = XV[j][1];                \
              float sA = accA[j][e], sB = accB[j][e];                   \
              sA = fmaf(x0.x, a0.x, sA); sA = fmaf(x0.y, a0.y, sA);     \
              sA = fmaf(x0.z, a0.z, sA); sA = fmaf(x0.w, a0.w, sA);     \
              sA = fmaf(x1.x, a1.x, sA); sA = fmaf(x1.y, a1.y, sA);     \
              sA = fmaf(x1.z, a1.z, sA); sA = fmaf(x1.w, a1.w, sA);     \
              sB = fmaf(x0.x, b0.x, sB); sB = fmaf(x0.y, b0.y, sB);     \
              sB = fmaf(x0.z, b0.z, sB); sB = fmaf(x0.w, b0.w, sB);     \
              sB = fmaf(x1.x, b1.x, sB); sB = fmaf(x1.y, b1.y, sB);     \
              sB = fmaf(x1.z, b1.z, sB); sB = fmaf(x1.w, b1.w, sB);     \
              accA[j][e] = sA; accB[j][e] = sB;                         \
          }                                                             \
      } }

    // prologue
    STAGE(wt0, 0);
    XLOAD(xA, 0);

    #pragma unroll 1
    for (int sp = 0; sp < NSTEP; sp += 2) {
        // even step sp: buffer wt0 / xA
        __syncthreads();                 // tile sp + x(sp) ready
        STAGE(wt1, sp + 1);
        XLOAD(xB, sp + 1);
        COMPUTE(wt0, xA);
        // odd step sp+1: buffer wt1 / xB
        __syncthreads();                 // tile sp+1 ready
        if (sp + 2 < NSTEP) {
            STAGE(wt0, sp + 2);
            XLOAD(xA, sp + 2);
        }
        COMPUTE(wt1, xB);
    }
#undef STAGE
#undef XLOAD
#undef COMPUTE

    // ---- butterfly over the 8 k-segs (masks 1,2,4 stay within seg-group) ----
    #pragma unroll
    for (int j = 0; j < 4; ++j)
        #pragma unroll
        for (int e = 0; e < NE; ++e) {
            float a = accA[j][e], b = accB[j][e];
            a += __shfl_xor(a, 1); a += __shfl_xor(a, 2); a += __shfl_xor(a, 4);
            b += __shfl_xor(b, 1); b += __shfl_xor(b, 2); b += __shfl_xor(b, 4);
            accA[j][e] = a; accB[j][e] = b;
        }

    __syncthreads();                  // all tile reads done; lds reusable
    float* const slab = lds;          // [4 groups][64 rows][32 outs]
    float* const red  = lds + 8192;   // [64 rows][stride 36]

    if (seg == 0) {
        const int rl = h * 32 + rgrp * 4;
        #pragma unroll
        for (int j = 0; j < 4; ++j) {
            float* dst = slab + g * 2048 + (rl + j) * 32;
            #pragma unroll
            for (int q = 0; q < 4; ++q) {
                *(float4*)(dst + q * 4)      = *(float4*)&accA[j][q * 4];
                *(float4*)(dst + 16 + q * 4) = *(float4*)&accB[j][q * 4];
            }
        }
    }
    __syncthreads();

    {   // combine 4 group-partials
        const int row = tid >> 3, q = tid & 7;
        float4 sum = make_float4(0.f, 0.f, 0.f, 0.f);
        #pragma unroll
        for (int gg = 0; gg < 4; ++gg) {
            const float4 v = *(const float4*)(slab + gg * 2048 + row * 32 + q * 4);
            sum.x += v.x; sum.y += v.y; sum.z += v.z; sum.w += v.w;
        }
        *(float4*)(red + row * 36 + q * 4) = sum;
    }
    __syncthreads();

    // ---- per-row epilogue: softplus noise, top-2, sparse softmax ----
    if (tid < ROWS_PER_BLK) {
        const int r = tid;
        float rv[32];
        #pragma unroll
        for (int q = 0; q < 8; ++q)
            *(float4*)&rv[q * 4] = *(const float4*)(red + r * 36 + q * 4);

        const size_t grow = (size_t)blockIdx.x * ROWS_PER_BLK + r;
        const float* nzp = noise + grow * NE;

        float m1 = -1e30f, m2 = -1e30f;
        int i1 = 0, i2 = 0;
        #pragma unroll
        for (int j = 0; j < NE; ++j) {
            const float z  = rv[16 + j] + bns[j];
            const float sp = fmaxf(z, 0.f) + log1pf(expf(-fabsf(z)));  // jax softplus
            const float v  = fmaf(nzp[j], sp, rv[j] + bfc[j]);
            if (v > m1)      { m2 = m1; i2 = i1; m1 = v; i1 = j; }     // ties -> lower idx
            else if (v > m2) { m2 = v;  i2 = j; }
        }
        const float e2  = expf(m2 - m1);
        const float inv = 1.f / (1.f + e2);

        float* po = out + grow * NE;
        #pragma unroll
        for (int j = 0; j < NE; ++j) {
            po[j] = (j == i1) ? inv : ((j == i2) ? e2 * inv : 0.f);
        }
        float* pi = out + (size_t)NROWS * NE + grow * 2;
        pi[0] = (float)i1;
        pi[1] = (float)i2;
    }
}

extern "C" void kernel_launch(void* const* d_in, const int* in_sizes, int n_in,
                              void* d_out, int out_size, void* d_ws, size_t ws_size,
                              hipStream_t stream)
{
    const float* x     = (const float*)d_in[0];
    const float* noise = (const float*)d_in[1];
    const float* Wfc   = (const float*)d_in[2];
    const float* bfc   = (const float*)d_in[3];
    const float* Wns   = (const float*)d_in[4];
    const float* bns   = (const float*)d_in[5];
    float* out = (float*)d_out;

    noisy_router_kernel<<<NROWS / ROWS_PER_BLK, 512, 0, stream>>>(
        x, noise, Wfc, bfc, Wns, bns, out);
}

// Round 10
// 241.181 us; speedup vs baseline: 1.0452x; 1.0129x over previous
//
#include <hip/hip_runtime.h>
#include <hip/hip_bf16.h>

#define NROWS 16384   // B*S
#define KD    2048    // D
#define NE    16      // experts
#define ROWS_PER_BLK 64
#define KQ    512     // K-range per K-group
#define TKG   64      // K-floats staged per group per step
#define NSTEP (KQ / TKG)   // 8

// v10 = v9 with __launch_bounds__(512, 1): hipcc applied block-count semantics
// to the 2nd arg (observed VGPR cap 128 = 512/(2 blk * 8 waves / 4 SIMD)),
// which forced ~100 regs of scratch spill (549 MB WRITE_SIZE). Budget 256 now.
//  - block = 512 thr / 8 waves; wave w -> (K-group g=w>>1, row-half h=w&1)
//  - lane = (rgrp=lane>>3 -> 4 rows, seg=lane&7 -> 8-float K-slice)
//  - per group: W-stack tile [32][64] double-buffered in LDS via global_load_lds
//  - FMA:ds_read = 16:1; ~4096 ds_read_b128/CU (~20us LDS floor)
// Output FLOAT32: [262144 probs][32768 ids-as-floats].

__device__ __forceinline__ void gload_lds16(const float* g, float* l) {
    __builtin_amdgcn_global_load_lds(
        (const __attribute__((address_space(1))) void*)g,
        (__attribute__((address_space(3))) void*)l,
        16, 0, 0);
}

__global__ __launch_bounds__(512, 1)
void noisy_router_kernel(const float* __restrict__ x,
                         const float* __restrict__ noise,
                         const float* __restrict__ Wfc,
                         const float* __restrict__ bfc,
                         const float* __restrict__ Wns,
                         const float* __restrict__ bns,
                         float* __restrict__ out)
{
    __shared__ float lds[16384];   // 64 KB: wt[4 groups][2 bufs][32*64]; epilogue reuse

    const int tid  = threadIdx.x;
    const int lane = tid & 63;
    const int w    = tid >> 6;     // 0..7
    const int g    = w >> 1;       // K-group 0..3
    const int h    = w & 1;        // row-half 0..1
    const int seg  = lane & 7;
    const int rgrp = lane >> 3;

    const int rowbase = blockIdx.x * ROWS_PER_BLK + h * 32 + rgrp * 4;
    const int kbase   = g * KQ;

    float* const wt0 = lds + (g * 2 + 0) * 2048;
    float* const wt1 = lds + (g * 2 + 1) * 2048;

    // staging map: wave stages W-stack rows h*16..h*16+15; instr i covers rows
    // srow+i*4 with col (lane&15)*4 -> LDS dest = uniform base + lane*16 bytes.
    const int srow = h * 16 + (lane >> 4);
    const int scol = (lane & 15) * 4;
    const float* wsrc[4];
    #pragma unroll
    for (int i = 0; i < 4; ++i) {
        const int wrow = srow + i * 4;
        wsrc[i] = (wrow < 16 ? Wfc + (size_t)wrow * KD
                             : Wns + (size_t)(wrow - 16) * KD) + kbase + scol;
    }
    const int sdst = srow * 64 + scol;   // +i*256 per instr

    const float* xptr[4];
    #pragma unroll
    for (int j = 0; j < 4; ++j)
        xptr[j] = x + (size_t)(rowbase + j) * KD + kbase + seg * 8;

    float accA[4][16], accB[4][16];
    #pragma unroll
    for (int j = 0; j < 4; ++j)
        #pragma unroll
        for (int e = 0; e < NE; ++e) { accA[j][e] = 0.f; accB[j][e] = 0.f; }

    float4 xA[4][2], xB[4][2];   // two named x buffers; all indices static

#define STAGE(DST, S)                                                   \
    { _Pragma("unroll")                                                 \
      for (int i = 0; i < 4; ++i)                                       \
          gload_lds16(wsrc[i] + (S) * TKG, (DST) + sdst + i * 256); }

#define XLOAD(XV, S)                                                    \
    { _Pragma("unroll")                                                 \
      for (int j = 0; j < 4; ++j) {                                     \
          XV[j][0] = *(const float4*)(xptr[j] + (S) * TKG);             \
          XV[j][1] = *(const float4*)(xptr[j] + (S) * TKG + 4);         \
      } }

#define COMPUTE(WT, XV)                                                 \
    { const float* wp = (WT) + seg * 8;                                 \
      _Pragma("unroll")                                                 \
      for (int e = 0; e < NE; ++e) {                                    \
          const float4 a0 = *(const float4*)(wp + e * 64);              \
          const float4 a1 = *(const float4*)(wp + e * 64 + 4);          \
          const float4 b0 = *(const float4*)(wp + (16 + e) * 64);       \
          const float4 b1 = *(const float4*)(wp + (16 + e) * 64 + 4);   \
          _Pragma("unroll")                                             \
          for (int j = 0; j < 4; ++j) {                                 \
              const float4 x0 = XV[j][0], x1 = XV[j][1];                \
              float sA = accA[j][e], sB = accB[j][e];                   \
              sA = fmaf(x0.x, a0.x, sA); sA = fmaf(x0.y, a0.y, sA);     \
              sA = fmaf(x0.z, a0.z, sA); sA = fmaf(x0.w, a0.w, sA);     \
              sA = fmaf(x1.x, a1.x, sA); sA = fmaf(x1.y, a1.y, sA);     \
              sA = fmaf(x1.z, a1.z, sA); sA = fmaf(x1.w, a1.w, sA);     \
              sB = fmaf(x0.x, b0.x, sB); sB = fmaf(x0.y, b0.y, sB);     \
              sB = fmaf(x0.z, b0.z, sB); sB = fmaf(x0.w, b0.w, sB);     \
              sB = fmaf(x1.x, b1.x, sB); sB = fmaf(x1.y, b1.y, sB);     \
              sB = fmaf(x1.z, b1.z, sB); sB = fmaf(x1.w, b1.w, sB);     \
              accA[j][e] = sA; accB[j][e] = sB;                         \
          }                                                             \
      } }

    // prologue
    STAGE(wt0, 0);
    XLOAD(xA, 0);

    #pragma unroll 1
    for (int sp = 0; sp < NSTEP; sp += 2) {
        // even step sp: buffer wt0 / xA
        __syncthreads();                 // tile sp + x(sp) ready
        STAGE(wt1, sp + 1);
        XLOAD(xB, sp + 1);
        COMPUTE(wt0, xA);
        // odd step sp+1: buffer wt1 / xB
        __syncthreads();                 // tile sp+1 ready
        if (sp + 2 < NSTEP) {
            STAGE(wt0, sp + 2);
            XLOAD(xA, sp + 2);
        }
        COMPUTE(wt1, xB);
    }
#undef STAGE
#undef XLOAD
#undef COMPUTE

    // ---- butterfly over the 8 k-segs (masks 1,2,4 stay within seg-group) ----
    #pragma unroll
    for (int j = 0; j < 4; ++j)
        #pragma unroll
        for (int e = 0; e < NE; ++e) {
            float a = accA[j][e], b = accB[j][e];
            a += __shfl_xor(a, 1); a += __shfl_xor(a, 2); a += __shfl_xor(a, 4);
            b += __shfl_xor(b, 1); b += __shfl_xor(b, 2); b += __shfl_xor(b, 4);
            accA[j][e] = a; accB[j][e] = b;
        }

    __syncthreads();                  // all tile reads done; lds reusable
    float* const slab = lds;          // [4 groups][64 rows][32 outs]
    float* const red  = lds + 8192;   // [64 rows][stride 36]

    if (seg == 0) {
        const int rl = h * 32 + rgrp * 4;
        #pragma unroll
        for (int j = 0; j < 4; ++j) {
            float* dst = slab + g * 2048 + (rl + j) * 32;
            #pragma unroll
            for (int q = 0; q < 4; ++q) {
                *(float4*)(dst + q * 4)      = *(float4*)&accA[j][q * 4];
                *(float4*)(dst + 16 + q * 4) = *(float4*)&accB[j][q * 4];
            }
        }
    }
    __syncthreads();

    {   // combine 4 group-partials
        const int row = tid >> 3, q = tid & 7;
        float4 sum = make_float4(0.f, 0.f, 0.f, 0.f);
        #pragma unroll
        for (int gg = 0; gg < 4; ++gg) {
            const float4 v = *(const float4*)(slab + gg * 2048 + row * 32 + q * 4);
            sum.x += v.x; sum.y += v.y; sum.z += v.z; sum.w += v.w;
        }
        *(float4*)(red + row * 36 + q * 4) = sum;
    }
    __syncthreads();

    // ---- per-row epilogue: softplus noise, top-2, sparse softmax ----
    if (tid < ROWS_PER_BLK) {
        const int r = tid;
        float rv[32];
        #pragma unroll
        for (int q = 0; q < 8; ++q)
            *(float4*)&rv[q * 4] = *(const float4*)(red + r * 36 + q * 4);

        const size_t grow = (size_t)blockIdx.x * ROWS_PER_BLK + r;
        const float* nzp = noise + grow * NE;

        float m1 = -1e30f, m2 = -1e30f;
        int i1 = 0, i2 = 0;
        #pragma unroll
        for (int j = 0; j < NE; ++j) {
            const float z  = rv[16 + j] + bns[j];
            const float sp = fmaxf(z, 0.f) + log1pf(expf(-fabsf(z)));  // jax softplus
            const float v  = fmaf(nzp[j], sp, rv[j] + bfc[j]);
            if (v > m1)      { m2 = m1; i2 = i1; m1 = v; i1 = j; }     // ties -> lower idx
            else if (v > m2) { m2 = v;  i2 = j; }
        }
        const float e2  = expf(m2 - m1);
        const float inv = 1.f / (1.f + e2);

        float* po = out + grow * NE;
        #pragma unroll
        for (int j = 0; j < NE; ++j) {
            po[j] = (j == i1) ? inv : ((j == i2) ? e2 * inv : 0.f);
        }
        float* pi = out + (size_t)NROWS * NE + grow * 2;
        pi[0] = (float)i1;
        pi[1] = (float)i2;
    }
}

extern "C" void kernel_launch(void* const* d_in, const int* in_sizes, int n_in,
                              void* d_out, int out_size, void* d_ws, size_t ws_size,
                              hipStream_t stream)
{
    const float* x     = (const float*)d_in[0];
    const float* noise = (const float*)d_in[1];
    const float* Wfc   = (const float*)d_in[2];
    const float* bfc   = (const float*)d_in[3];
    const float* Wns   = (const float*)d_in[4];
    const float* bns   = (const float*)d_in[5];
    float* out = (float*)d_out;

    noisy_router_kernel<<<NROWS / ROWS_PER_BLK, 512, 0, stream>>>(
        x, noise, Wfc, bfc, Wns, bns, out);
}